// Round 13
// baseline (1088.801 us; speedup 1.0000x reference)
//
#include <hip/hip_runtime.h>
#include <math.h>

// Problem constants
#define BB 4
#define NN 1000
#define TT 8
#define FF 64
#define HH 64
#define NHEADS 4
#define EE 16000
#define E2 17000          // EE + NN self-loops (EXACT per-graph edge total)
#define GG (BB*TT)        // 32 graphs
#define GN (GG*NN)        // 32000 (graph,node) pairs
#define NROWS (BB*NN)     // 4000 GRU rows

// ---------------- helpers ----------------
__device__ __forceinline__ float sigmoidf_(float x) {
    return 1.f / (1.f + __expf(-x));
}
__device__ __forceinline__ float tanhf_(float x) {
    x = fminf(fmaxf(x, -15.f), 15.f);
    float e = __expf(2.f * x);
    return (e - 1.f) / (e + 1.f);
}
__device__ __forceinline__ float leaky_(float x) {
    return (x > 0.f) ? x : 0.2f * x;
}

// ---------------- CSR build ----------------
__global__ void count_edges(const int* __restrict__ ei, int* __restrict__ counts) {
    int g = blockIdx.y;
    int e = blockIdx.x * 256 + threadIdx.x;
    if (e >= E2) return;
    int dst;
    if (e < EE) dst = ei[(size_t)g * 2 * EE + EE + e];
    else        dst = e - EE;   // self-loop
    atomicAdd(&counts[g * NN + dst], 1);
}

// Per-graph scan: each graph owns csr region [g*E2, (g+1)*E2); only a
// 1000-element scan per graph is needed. One 256-thread block per graph.
__global__ __launch_bounds__(256) void scan_offsets_pg(const int* __restrict__ counts,
                                                       int* __restrict__ offs) {
    __shared__ int tot[256];
    int g = blockIdx.x;
    int tid = threadIdx.x;
    int base = tid * 4;
    int c0 = 0, c1 = 0, c2 = 0, c3 = 0;
    if (base < NN) {
        int4 v = *(const int4*)(counts + (size_t)g * NN + base);  // 16B aligned (NN%4==0)
        c0 = v.x; c1 = v.y; c2 = v.z; c3 = v.w;
    }
    int s = c0 + c1 + c2 + c3;
    tot[tid] = s;
    __syncthreads();
    // Hillis-Steele inclusive scan over 256 partials
    for (int off = 1; off < 256; off <<= 1) {
        int y = (tid >= off) ? tot[tid - off] : 0;
        __syncthreads();
        tot[tid] += y;
        __syncthreads();
    }
    int run = g * E2 + tot[tid] - s;  // exclusive prefix + graph base
    if (base < NN) {
        int4 o;
        o.x = run; run += c0;
        o.y = run; run += c1;
        o.z = run; run += c2;
        o.w = run;
        *(int4*)(offs + (size_t)g * NN + base) = o;
    }
    if (g == 0 && tid == 0) offs[GN] = GG * E2;
}

__global__ void scatter_edges(const int* __restrict__ ei, const int* __restrict__ offs,
                              int* __restrict__ cursor, int* __restrict__ csr) {
    int g = blockIdx.y;
    int e = blockIdx.x * 256 + threadIdx.x;
    if (e >= E2) return;
    int src, dst;
    if (e < EE) {
        src = ei[(size_t)g * 2 * EE + e];
        dst = ei[(size_t)g * 2 * EE + EE + e];
    } else {
        src = dst = e - EE;
    }
    int i = g * NN + dst;
    int pos = offs[i] + atomicAdd(&cursor[i], 1);
    csr[pos] = src;
}

// Register pin (used by gru_gi; kept from R7 to avoid confounds there)
#define PIN64_(arr)                                        \
    _Pragma("unroll")                                      \
    for (int _pi = 0; _pi < 64; ++_pi)                     \
        asm volatile("" : "+v"((arr)[_pi]));

// ---------------- fold att into W: WA[layer][sd][head][f] ----------------
// asrc = (x@W)·a_src == x@(W·a_src): precompute WA so the per-node attention
// logits become plain dot products.
__global__ void compute_wa(const float* __restrict__ W1, const float* __restrict__ as1,
                           const float* __restrict__ ad1,
                           const float* __restrict__ W2, const float* __restrict__ as2,
                           const float* __restrict__ ad2, float* __restrict__ WA) {
    int t = threadIdx.x;       // 256 threads
    int f = t >> 2, head = t & 3;
    float s1 = 0.f, d1 = 0.f, s2 = 0.f, d2 = 0.f;
    for (int ch = 0; ch < 64; ++ch) {
        float w1 = W1[f * 256 + head * 64 + ch];
        float w2 = W2[f * 256 + head * 64 + ch];
        s1 = fmaf(w1, as1[head * 64 + ch], s1);
        d1 = fmaf(w1, ad1[head * 64 + ch], d1);
        s2 = fmaf(w2, as2[head * 64 + ch], s2);
        d2 = fmaf(w2, ad2[head * 64 + ch], d2);
    }
    WA[        head * 64 + f] = s1;   // layer0 src
    WA[256 +   head * 64 + f] = d1;   // layer0 dst
    WA[512 +   head * 64 + f] = s2;   // layer1 src
    WA[768 +   head * 64 + f] = d2;   // layer1 dst
}

// ---------------- attention logits: asrc/adst[node][head] = x_row . WA ----------------
// 64 nodes/block, thread = (node, head); coalesced stores. ~16 MFLOP total.
template <int MODE>
__global__ __launch_bounds__(256) void gat_att(
    const float* __restrict__ in, const float* __restrict__ WA,
    float* __restrict__ asrc, float* __restrict__ adst) {
    __shared__ float wab[8][64];   // [sd*4+head][f]
    int tid = threadIdx.x;
    for (int i = tid; i < 512; i += 256) ((float*)wab)[i] = WA[i];
    __syncthreads();
    int node = blockIdx.x * 64 + (tid >> 2);
    int head = tid & 3;
    int g = node / NN, nn = node - g * NN;
    const float* xrow;
    if (MODE == 0) {
        int b = g / TT, t = g % TT;
        xrow = in + (((size_t)(b * NN + nn) * TT + t) << 6);
    } else {
        xrow = in + ((size_t)node << 6);
    }
    float accs = 0.f, accd = 0.f;
#pragma unroll
    for (int f4 = 0; f4 < 16; ++f4) {
        float4 xv = *(const float4*)(xrow + f4 * 4);
        float4 ws = *(const float4*)&wab[head][f4 * 4];
        float4 wd = *(const float4*)&wab[4 + head][f4 * 4];
        accs = fmaf(xv.x, ws.x, accs); accs = fmaf(xv.y, ws.y, accs);
        accs = fmaf(xv.z, ws.z, accs); accs = fmaf(xv.w, ws.w, accs);
        accd = fmaf(xv.x, wd.x, accd); accd = fmaf(xv.y, wd.y, accd);
        accd = fmaf(xv.z, wd.z, accd); accd = fmaf(xv.w, wd.w, accd);
    }
    asrc[(size_t)node * 4 + head] = accs;
    adst[(size_t)node * 4 + head] = accd;
}

// ---------------- GAT linear v9: v8 body + occupancy pin ----------------
// R12 lesson: without the shuffle tail the compiler kept wcol resident
// (VGPR 104) and occupancy crashed 35%->18% => 72us. This kernel's economics
// are occupancy x latency-hiding: __launch_bounds__(256,8) caps VGPR at 64,
// forcing the proven 44-VGPR reload codegen, with the no-shuffle body.
// hlin layout: [node][chan][head] (head fastest, float4 per chan)
// MODE 0: input is x [B,N,T,F] gathered per graph g=(b,t).  MODE 1: input [G,N,F] contiguous.
template <int MODE>
__global__ __launch_bounds__(256, 8) void gat_linear(
    const float* __restrict__ in, const float* __restrict__ W,
    float* __restrict__ hlin) {
    const int ROWS = 10;
    const int CH = NN / ROWS;  // 100 -> 3200 blocks
    int g = blockIdx.x / CH;
    int n0 = (blockIdx.x % CH) * ROWS;
    int tid = threadIdx.x;
    // W column: W[f][tid]
    float wcol[FF];
#pragma unroll
    for (int f = 0; f < FF; ++f) wcol[f] = W[f * 256 + tid];
    int head = tid >> 6, lane = tid & 63;
    int b = g / TT, t = g % TT;
    for (int r = 0; r < ROWS; ++r) {
        int n = n0 + r;
        const float* xrow;
        if (MODE == 0) xrow = in + (((size_t)(b * NN + n) * TT + t) * FF);
        else           xrow = in + ((size_t)(g * NN + n) * FF);
        float a0 = 0.f, a1 = 0.f, a2 = 0.f, a3 = 0.f;
#pragma unroll
        for (int f = 0; f < 16; ++f) {
            a0 = fmaf(xrow[f],      wcol[f],      a0);
            a1 = fmaf(xrow[16 + f], wcol[16 + f], a1);
            a2 = fmaf(xrow[32 + f], wcol[32 + f], a2);
            a3 = fmaf(xrow[48 + f], wcol[48 + f], a3);
        }
        float acc = (a0 + a1) + (a2 + a3);
        // transposed store: [node][chan=lane][head]
        hlin[((size_t)(g * NN + n) << 8) + (lane << 2) + head] = acc;
    }
}

// ---------------- GAT edge softmax + aggregation (v3: 8-way MLP phase B; FROZEN) ----------------
__global__ __launch_bounds__(256) void gat_edge(
    const float* __restrict__ hlin, const float* __restrict__ asrc,
    const float* __restrict__ adst, const int* __restrict__ offs,
    const int* __restrict__ csr, const float* __restrict__ bias,
    float* __restrict__ out, int do_relu) {
    __shared__ float pbuf[4][64][4];   // [wave][edge-in-chunk][head]
    __shared__ int   sbuf[4][64];
    __shared__ int   degs[4];
    int tid = threadIdx.x;
    int lane = tid & 63, w = tid >> 6;
    // XCD swizzle: graph g -> XCD g%8 (consecutive blockIdx round-robins XCDs)
    int B = blockIdx.x;
    int x = B & 7, j = B >> 3;             // j in 0..999
    int graph = x + 8 * (j / 250);
    int node = graph * NN + ((j % 250) << 2) + w;
    int beg = offs[node], end = offs[node + 1];
    int deg = end - beg;
    if (lane == 0) degs[w] = deg;
    __syncthreads();
    int maxdeg = max(max(degs[0], degs[1]), max(degs[2], degs[3]));
    int nchunk = (maxdeg + 63) >> 6;

    float4 ad = *(const float4*)(adst + (size_t)node * 4);
    const float* asrc_g = asrc + (size_t)graph * NN * 4;
    const float* hg = hlin + ((size_t)graph * NN << 8);

    float4 acc = make_float4(0.f, 0.f, 0.f, 0.f);
    float4 ssum = make_float4(0.f, 0.f, 0.f, 0.f);
    for (int c = 0; c < nchunk; ++c) {
        int e0 = beg + (c << 6);
        int myedge = e0 + lane;
        float4 p = make_float4(0.f, 0.f, 0.f, 0.f);
        int src = 0;
        if (myedge < end) {
            src = csr[myedge];
            float4 a = *(const float4*)(asrc_g + (size_t)src * 4);
            p.x = __expf(leaky_(a.x + ad.x));
            p.y = __expf(leaky_(a.y + ad.y));
            p.z = __expf(leaky_(a.z + ad.z));
            p.w = __expf(leaky_(a.w + ad.w));
        }
        // butterfly sum of this chunk's weights
        float4 t = p;
#pragma unroll
        for (int off = 1; off < 64; off <<= 1) {
            t.x += __shfl_xor(t.x, off, 64);
            t.y += __shfl_xor(t.y, off, 64);
            t.z += __shfl_xor(t.z, off, 64);
            t.w += __shfl_xor(t.w, off, 64);
        }
        ssum.x += t.x; ssum.y += t.y; ssum.z += t.z; ssum.w += t.w;
        *(float4*)&pbuf[w][lane][0] = p;
        sbuf[w][lane] = src;
        __syncthreads();
        int cnt = end - e0;
        if (cnt > 64) cnt = 64;
        int cnt8 = (cnt + 7) & ~7;         // pad to x8: pbuf/sbuf zero-filled
        for (int e = 0; e < cnt8; e += 8) {
            float4 p0 = *(const float4*)&pbuf[w][e + 0][0];
            float4 p1 = *(const float4*)&pbuf[w][e + 1][0];
            float4 p2 = *(const float4*)&pbuf[w][e + 2][0];
            float4 p3 = *(const float4*)&pbuf[w][e + 3][0];
            float4 p4 = *(const float4*)&pbuf[w][e + 4][0];
            float4 p5 = *(const float4*)&pbuf[w][e + 5][0];
            float4 p6 = *(const float4*)&pbuf[w][e + 6][0];
            float4 p7 = *(const float4*)&pbuf[w][e + 7][0];
            int s0 = sbuf[w][e + 0], s1 = sbuf[w][e + 1];
            int s2 = sbuf[w][e + 2], s3 = sbuf[w][e + 3];
            int s4 = sbuf[w][e + 4], s5 = sbuf[w][e + 5];
            int s6 = sbuf[w][e + 6], s7 = sbuf[w][e + 7];
            int lo = lane << 2;
            float4 h0 = *(const float4*)(hg + (((size_t)s0) << 8) + lo);
            float4 h1 = *(const float4*)(hg + (((size_t)s1) << 8) + lo);
            float4 h2 = *(const float4*)(hg + (((size_t)s2) << 8) + lo);
            float4 h3 = *(const float4*)(hg + (((size_t)s3) << 8) + lo);
            float4 h4 = *(const float4*)(hg + (((size_t)s4) << 8) + lo);
            float4 h5 = *(const float4*)(hg + (((size_t)s5) << 8) + lo);
            float4 h6 = *(const float4*)(hg + (((size_t)s6) << 8) + lo);
            float4 h7 = *(const float4*)(hg + (((size_t)s7) << 8) + lo);
            acc.x = fmaf(p0.x, h0.x, acc.x); acc.y = fmaf(p0.y, h0.y, acc.y);
            acc.z = fmaf(p0.z, h0.z, acc.z); acc.w = fmaf(p0.w, h0.w, acc.w);
            acc.x = fmaf(p1.x, h1.x, acc.x); acc.y = fmaf(p1.y, h1.y, acc.y);
            acc.z = fmaf(p1.z, h1.z, acc.z); acc.w = fmaf(p1.w, h1.w, acc.w);
            acc.x = fmaf(p2.x, h2.x, acc.x); acc.y = fmaf(p2.y, h2.y, acc.y);
            acc.z = fmaf(p2.z, h2.z, acc.z); acc.w = fmaf(p2.w, h2.w, acc.w);
            acc.x = fmaf(p3.x, h3.x, acc.x); acc.y = fmaf(p3.y, h3.y, acc.y);
            acc.z = fmaf(p3.z, h3.z, acc.z); acc.w = fmaf(p3.w, h3.w, acc.w);
            acc.x = fmaf(p4.x, h4.x, acc.x); acc.y = fmaf(p4.y, h4.y, acc.y);
            acc.z = fmaf(p4.z, h4.z, acc.z); acc.w = fmaf(p4.w, h4.w, acc.w);
            acc.x = fmaf(p5.x, h5.x, acc.x); acc.y = fmaf(p5.y, h5.y, acc.y);
            acc.z = fmaf(p5.z, h5.z, acc.z); acc.w = fmaf(p5.w, h5.w, acc.w);
            acc.x = fmaf(p6.x, h6.x, acc.x); acc.y = fmaf(p6.y, h6.y, acc.y);
            acc.z = fmaf(p6.z, h6.z, acc.z); acc.w = fmaf(p6.w, h6.w, acc.w);
            acc.x = fmaf(p7.x, h7.x, acc.x); acc.y = fmaf(p7.y, h7.y, acc.y);
            acc.z = fmaf(p7.z, h7.z, acc.z); acc.w = fmaf(p7.w, h7.w, acc.w);
        }
        __syncthreads();
    }
    float o = 0.25f * (acc.x / ssum.x + acc.y / ssum.y + acc.z / ssum.z + acc.w / ssum.w)
            + bias[lane];
    if (do_relu) o = fmaxf(o, 0.f);
    out[((size_t)node << 6) + lane] = o;
}

// ---------------- GRU input-side GEMM (FROZEN) ----------------
template <int MODE>
__global__ __launch_bounds__(192, 4) void gru_gi(
    const float* __restrict__ in, const float* __restrict__ Wih,
    const float* __restrict__ bih, float* __restrict__ giseq) {
    const int ROWS = 10;  // 3200 blocks * 10 = 32000 (t,row) pairs
    int j = threadIdx.x;  // 0..191
    float wrow[64];
#pragma unroll
    for (int f4 = 0; f4 < 16; ++f4) {
        float4 w = *(const float4*)(Wih + (size_t)j * 64 + f4 * 4);
        wrow[4 * f4 + 0] = w.x; wrow[4 * f4 + 1] = w.y;
        wrow[4 * f4 + 2] = w.z; wrow[4 * f4 + 3] = w.w;
    }
    PIN64_(wrow)
    float bj = bih[j];
    int q0 = blockIdx.x * ROWS;
    int t = q0 / NROWS;            // constant per block (NROWS % ROWS == 0)
    int r0 = q0 - t * NROWS;
    for (int rr = 0; rr < ROWS; rr += 2) {
        const float *xa, *xb;
        if (MODE == 0) {
            int ra = r0 + rr, rb = ra + 1;
            int ba = ra / NN, na = ra - ba * NN;
            int bb2 = rb / NN, nb = rb - bb2 * NN;
            xa = in + (((size_t)(ba * TT + t) * NN + na) << 6);
            xb = in + (((size_t)(bb2 * TT + t) * NN + nb) << 6);
        } else {
            xa = in + ((size_t)(q0 + rr) << 6);
            xb = xa + 64;
        }
        float acca = bj, accb = bj;
#pragma unroll
        for (int f4 = 0; f4 < 16; ++f4) {
            float4 a4 = *(const float4*)(xa + f4 * 4);
            float4 b4 = *(const float4*)(xb + f4 * 4);
            acca = fmaf(a4.x, wrow[4 * f4 + 0], acca);
            acca = fmaf(a4.y, wrow[4 * f4 + 1], acca);
            acca = fmaf(a4.z, wrow[4 * f4 + 2], acca);
            acca = fmaf(a4.w, wrow[4 * f4 + 3], acca);
            accb = fmaf(b4.x, wrow[4 * f4 + 0], accb);
            accb = fmaf(b4.y, wrow[4 * f4 + 1], accb);
            accb = fmaf(b4.z, wrow[4 * f4 + 2], accb);
            accb = fmaf(b4.w, wrow[4 * f4 + 3], accb);
        }
        giseq[(size_t)(q0 + rr) * 192 + j] = acca;
        giseq[(size_t)(q0 + rr + 1) * 192 + j] = accb;
    }
}

// ---------------- GRU recurrence v2 (FROZEN) ----------------
template <int LAYER>
__global__ __launch_bounds__(128) void gru_rec(
    const float* __restrict__ giseq, const float* __restrict__ Whh,
    const float* __restrict__ bhh, float* __restrict__ outseq) {
    __shared__ float hs[8][64];       // 2 waves * 4 rows, wave-private regions
    int tid = threadIdx.x;
    int ch = tid & 63, w = tid >> 6;  // w in {0,1}
    float wr[64], wz[64], wn[64];
#pragma unroll
    for (int k4 = 0; k4 < 16; ++k4) {
        float4 a = *(const float4*)(Whh + (size_t)ch * 64 + k4 * 4);
        float4 b = *(const float4*)(Whh + (size_t)(64 + ch) * 64 + k4 * 4);
        float4 c = *(const float4*)(Whh + (size_t)(128 + ch) * 64 + k4 * 4);
        wr[4*k4+0] = a.x; wr[4*k4+1] = a.y; wr[4*k4+2] = a.z; wr[4*k4+3] = a.w;
        wz[4*k4+0] = b.x; wz[4*k4+1] = b.y; wz[4*k4+2] = b.z; wz[4*k4+3] = b.w;
        wn[4*k4+0] = c.x; wn[4*k4+1] = c.y; wn[4*k4+2] = c.z; wn[4*k4+3] = c.w;
    }
    float br = bhh[ch], bz = bhh[64 + ch], bn = bhh[128 + ch];
    int row0 = blockIdx.x * 8 + w * 4;
    float hprev[4];
#pragma unroll
    for (int r = 0; r < 4; ++r) { hs[w * 4 + r][ch] = 0.f; hprev[r] = 0.f; }

    for (int t = 0; t < TT; ++t) {
#pragma unroll
        for (int r = 0; r < 4; ++r) {
            int row = row0 + r;
            const float* gp = giseq + ((size_t)(t * NROWS + row)) * 192;
            float gir = gp[ch], giz = gp[64 + ch], gin = gp[128 + ch];
            float ar = br, az = bz, an = bn;
#pragma unroll
            for (int k4 = 0; k4 < 16; ++k4) {
                float4 h4 = *(const float4*)&hs[w * 4 + r][k4 * 4];  // broadcast
                ar = fmaf(h4.x, wr[4*k4+0], ar); ar = fmaf(h4.y, wr[4*k4+1], ar);
                ar = fmaf(h4.z, wr[4*k4+2], ar); ar = fmaf(h4.w, wr[4*k4+3], ar);
                az = fmaf(h4.x, wz[4*k4+0], az); az = fmaf(h4.y, wz[4*k4+1], az);
                az = fmaf(h4.z, wz[4*k4+2], az); az = fmaf(h4.w, wz[4*k4+3], az);
                an = fmaf(h4.x, wn[4*k4+0], an); an = fmaf(h4.y, wn[4*k4+1], an);
                an = fmaf(h4.z, wn[4*k4+2], an); an = fmaf(h4.w, wn[4*k4+3], an);
            }
            float rg = sigmoidf_(gir + ar);
            float zg = sigmoidf_(giz + az);
            float ng = tanhf_(gin + rg * an);
            float hnew = (1.f - zg) * ng + zg * hprev[r];
            hprev[r] = hnew;
            hs[w * 4 + r][ch] = hnew;   // same-wave LDS dep, compiler orders via lgkmcnt
            if (LAYER == 0)
                outseq[(((size_t)(t * NROWS + row)) << 6) + ch] = hnew;
        }
    }
    if (LAYER == 1) {
#pragma unroll
        for (int r = 0; r < 4; ++r)
            outseq[(((size_t)(row0 + r)) << 6) + ch] = hprev[r];
    }
}

// ---------------- final MLP ----------------
__global__ __launch_bounds__(64) void mlp_head(
    const float* __restrict__ hT, const float* __restrict__ pW1,
    const float* __restrict__ pb1, const float* __restrict__ pW2,
    const float* __restrict__ pb2, float* __restrict__ out) {
    int r = blockIdx.x, lane = threadIdx.x;
    __shared__ float hrow[64];
    __shared__ float mid[64];
    hrow[lane] = hT[((size_t)r << 6) + lane];
    __syncthreads();
    float acc = pb1[lane];
#pragma unroll
    for (int k = 0; k < 64; ++k) acc = fmaf(hrow[k], pW1[k * 64 + lane], acc);
    mid[lane] = fmaxf(acc, 0.f);
    __syncthreads();
    if (lane < 10) {
        float o = pb2[lane];
#pragma unroll
        for (int k = 0; k < 64; ++k) o = fmaf(mid[k], pW2[k * 10 + lane], o);
        out[(size_t)r * 10 + lane] = o;
    }
}

// ---------------- launch ----------------
extern "C" void kernel_launch(void* const* d_in, const int* in_sizes, int n_in,
                              void* d_out, int out_size, void* d_ws, size_t ws_size,
                              hipStream_t stream) {
    (void)in_sizes; (void)n_in; (void)out_size; (void)ws_size;
    const float* x    = (const float*)d_in[0];
    const int*   ei   = (const int*)d_in[1];
    const float* W1   = (const float*)d_in[3];
    const float* as1  = (const float*)d_in[4];
    const float* ad1  = (const float*)d_in[5];
    const float* b1   = (const float*)d_in[6];
    const float* W2   = (const float*)d_in[7];
    const float* as2  = (const float*)d_in[8];
    const float* ad2  = (const float*)d_in[9];
    const float* b2   = (const float*)d_in[10];
    const float* Wih0 = (const float*)d_in[13];
    const float* Whh0 = (const float*)d_in[14];
    const float* bih0 = (const float*)d_in[15];
    const float* bhh0 = (const float*)d_in[16];
    const float* Wih1 = (const float*)d_in[17];
    const float* Whh1 = (const float*)d_in[18];
    const float* bih1 = (const float*)d_in[19];
    const float* bhh1 = (const float*)d_in[20];
    const float* pW1  = (const float*)d_in[21];
    const float* pb1  = (const float*)d_in[22];
    const float* pW2  = (const float*)d_in[23];
    const float* pb2  = (const float*)d_in[24];
    float* out = (float*)d_out;

    // workspace layout (bytes); overlays noted
    char* ws = (char*)d_ws;
    float* hlin  = (float*)(ws + 0);           // 32,768,000  (overlay: giseq 24.58MB)
    float* giseq = hlin;
    float* asrc  = (float*)(ws + 32768000);    // 512,000     (overlay: hT 1MB spans asrc+adst)
    float* hT    = asrc;
    float* adst  = (float*)(ws + 33280000);    // 512,000
    float* gat1  = (float*)(ws + 33792000);    // 8,192,000   (overlay: h1seq)
    float* h1seq = gat1;
    float* gat2  = (float*)(ws + 41984000);    // 8,192,000
    int* counts  = (int*)(ws + 50176000);      // 128,000
    int* cursor  = (int*)(ws + 50304000);      // 128,000
    int* offs    = (int*)(ws + 50432000);      // 128,004 (padded to 128,256)
    int* csr     = (int*)(ws + 50560256);      // 2,176,000
    float* WA    = (float*)(ws + 52736256);    // 4,096 -> total ~52.74MB

    hipMemsetAsync(counts, 0, 2 * GN * sizeof(int), stream);  // counts + cursor (adjacent)

    dim3 egrid((E2 + 255) / 256, GG);
    count_edges<<<egrid, 256, 0, stream>>>(ei, counts);
    scan_offsets_pg<<<GG, 256, 0, stream>>>(counts, offs);
    scatter_edges<<<egrid, 256, 0, stream>>>(ei, offs, cursor, csr);
    compute_wa<<<1, 256, 0, stream>>>(W1, as1, ad1, W2, as2, ad2, WA);

    gat_linear<0><<<GG * 100, 256, 0, stream>>>(x, W1, hlin);
    gat_att<0><<<GN / 64, 256, 0, stream>>>(x, WA, asrc, adst);
    gat_edge<<<GN / 4, 256, 0, stream>>>(hlin, asrc, adst, offs, csr, b1, gat1, 1);
    gat_linear<1><<<GG * 100, 256, 0, stream>>>(gat1, W2, hlin);
    gat_att<1><<<GN / 64, 256, 0, stream>>>(gat1, WA + 512, asrc, adst);
    gat_edge<<<GN / 4, 256, 0, stream>>>(hlin, asrc, adst, offs, csr, b2, gat2, 0);

    gru_gi<0><<<3200, 192, 0, stream>>>(gat2, Wih0, bih0, giseq);
    gru_rec<0><<<500, 128, 0, stream>>>(giseq, Whh0, bhh0, h1seq);
    gru_gi<1><<<3200, 192, 0, stream>>>(h1seq, Wih1, bih1, giseq);
    gru_rec<1><<<500, 128, 0, stream>>>(giseq, Whh1, bhh1, hT);

    mlp_head<<<NROWS, 64, 0, stream>>>(hT, pW1, pb1, pW2, pb2, out);
}

// Round 14
// 433.099 us; speedup vs baseline: 2.5140x; 2.5140x over previous
//
#include <hip/hip_runtime.h>
#include <math.h>

// Problem constants
#define BB 4
#define NN 1000
#define TT 8
#define FF 64
#define HH 64
#define NHEADS 4
#define EE 16000
#define E2 17000          // EE + NN self-loops (EXACT per-graph edge total)
#define GG (BB*TT)        // 32 graphs
#define GN (GG*NN)        // 32000 (graph,node) pairs
#define NROWS (BB*NN)     // 4000 GRU rows

// ---------------- helpers ----------------
__device__ __forceinline__ float sigmoidf_(float x) {
    return 1.f / (1.f + __expf(-x));
}
__device__ __forceinline__ float tanhf_(float x) {
    x = fminf(fmaxf(x, -15.f), 15.f);
    float e = __expf(2.f * x);
    return (e - 1.f) / (e + 1.f);
}
__device__ __forceinline__ float leaky_(float x) {
    return (x > 0.f) ? x : 0.2f * x;
}

// ---------------- CSR build ----------------
__global__ void count_edges(const int* __restrict__ ei, int* __restrict__ counts) {
    int g = blockIdx.y;
    int e = blockIdx.x * 256 + threadIdx.x;
    if (e >= E2) return;
    int dst;
    if (e < EE) dst = ei[(size_t)g * 2 * EE + EE + e];
    else        dst = e - EE;   // self-loop
    atomicAdd(&counts[g * NN + dst], 1);
}

// Per-graph scan: each graph owns csr region [g*E2, (g+1)*E2); only a
// 1000-element scan per graph is needed. One 256-thread block per graph.
__global__ __launch_bounds__(256) void scan_offsets_pg(const int* __restrict__ counts,
                                                       int* __restrict__ offs) {
    __shared__ int tot[256];
    int g = blockIdx.x;
    int tid = threadIdx.x;
    int base = tid * 4;
    int c0 = 0, c1 = 0, c2 = 0, c3 = 0;
    if (base < NN) {
        int4 v = *(const int4*)(counts + (size_t)g * NN + base);  // 16B aligned (NN%4==0)
        c0 = v.x; c1 = v.y; c2 = v.z; c3 = v.w;
    }
    int s = c0 + c1 + c2 + c3;
    tot[tid] = s;
    __syncthreads();
    // Hillis-Steele inclusive scan over 256 partials
    for (int off = 1; off < 256; off <<= 1) {
        int y = (tid >= off) ? tot[tid - off] : 0;
        __syncthreads();
        tot[tid] += y;
        __syncthreads();
    }
    int run = g * E2 + tot[tid] - s;  // exclusive prefix + graph base
    if (base < NN) {
        int4 o;
        o.x = run; run += c0;
        o.y = run; run += c1;
        o.z = run; run += c2;
        o.w = run;
        *(int4*)(offs + (size_t)g * NN + base) = o;
    }
    if (g == 0 && tid == 0) offs[GN] = GG * E2;
}

__global__ void scatter_edges(const int* __restrict__ ei, const int* __restrict__ offs,
                              int* __restrict__ cursor, int* __restrict__ csr) {
    int g = blockIdx.y;
    int e = blockIdx.x * 256 + threadIdx.x;
    if (e >= E2) return;
    int src, dst;
    if (e < EE) {
        src = ei[(size_t)g * 2 * EE + e];
        dst = ei[(size_t)g * 2 * EE + EE + e];
    } else {
        src = dst = e - EE;
    }
    int i = g * NN + dst;
    int pos = offs[i] + atomicAdd(&cursor[i], 1);
    csr[pos] = src;
}

// Register pin (used by gru_gi; kept from R7 to avoid confounds there)
#define PIN64_(arr)                                        \
    _Pragma("unroll")                                      \
    for (int _pi = 0; _pi < 64; ++_pi)                     \
        asm volatile("" : "+v"((arr)[_pi]));

// ---------------- GAT linear (R9-measured best config; FROZEN) ----------------
// v2 body: wcol strided loads, wave-uniform scalar x loads (s_load +
// v_fmac-with-SGPR), butterfly tail, ROWS=10, bare launch_bounds(256).
// This is a fragile 44-VGPR local optimum: R10 (LDS x-tile) neutral,
// R11 (4-chain) neutral, R12 (no-shuffle split) 104 VGPR/18% occ -> 72us,
// R13 ((256,8) cap) scratch spill -> 357us. DO NOT PERTURB.
// hlin layout: [node][chan][head] (head fastest, float4 per chan)
// MODE 0: input is x [B,N,T,F] gathered per graph g=(b,t).  MODE 1: input [G,N,F] contiguous.
template <int MODE>
__global__ __launch_bounds__(256) void gat_linear(
    const float* __restrict__ in, const float* __restrict__ W,
    const float* __restrict__ att_s, const float* __restrict__ att_d,
    float* __restrict__ hlin, float* __restrict__ asrc, float* __restrict__ adst) {
    const int ROWS = 10;
    const int CH = NN / ROWS;  // 100 -> 3200 blocks
    int g = blockIdx.x / CH;
    int n0 = (blockIdx.x % CH) * ROWS;
    int tid = threadIdx.x;
    // W column into registers: W[f][tid]
    float wcol[FF];
#pragma unroll
    for (int f = 0; f < FF; ++f) wcol[f] = W[f * 256 + tid];
    int head = tid >> 6, lane = tid & 63;
    float as = att_s[head * HH + lane];
    float ad = att_d[head * HH + lane];
    int b = g / TT, t = g % TT;
    for (int r = 0; r < ROWS; ++r) {
        int n = n0 + r;
        const float* xrow;
        if (MODE == 0) xrow = in + (((size_t)(b * NN + n) * TT + t) * FF);
        else           xrow = in + ((size_t)(g * NN + n) * FF);
        float acc = 0.f;
#pragma unroll
        for (int f = 0; f < FF; ++f) acc = fmaf(xrow[f], wcol[f], acc);
        // transposed store: [node][chan=lane][head]
        hlin[((size_t)(g * NN + n) << 8) + (lane << 2) + head] = acc;
        float s1 = acc * as, s2 = acc * ad;
#pragma unroll
        for (int off = 32; off; off >>= 1) {
            s1 += __shfl_xor(s1, off, 64);
            s2 += __shfl_xor(s2, off, 64);
        }
        if (lane == 0) {
            asrc[(size_t)(g * NN + n) * NHEADS + head] = s1;
            adst[(size_t)(g * NN + n) * NHEADS + head] = s2;
        }
    }
}

// ---------------- GAT edge softmax + aggregation (v3: 8-way MLP phase B; FROZEN) ----------------
__global__ __launch_bounds__(256) void gat_edge(
    const float* __restrict__ hlin, const float* __restrict__ asrc,
    const float* __restrict__ adst, const int* __restrict__ offs,
    const int* __restrict__ csr, const float* __restrict__ bias,
    float* __restrict__ out, int do_relu) {
    __shared__ float pbuf[4][64][4];   // [wave][edge-in-chunk][head]
    __shared__ int   sbuf[4][64];
    __shared__ int   degs[4];
    int tid = threadIdx.x;
    int lane = tid & 63, w = tid >> 6;
    // XCD swizzle: graph g -> XCD g%8 (consecutive blockIdx round-robins XCDs)
    int B = blockIdx.x;
    int x = B & 7, j = B >> 3;             // j in 0..999
    int graph = x + 8 * (j / 250);
    int node = graph * NN + ((j % 250) << 2) + w;
    int beg = offs[node], end = offs[node + 1];
    int deg = end - beg;
    if (lane == 0) degs[w] = deg;
    __syncthreads();
    int maxdeg = max(max(degs[0], degs[1]), max(degs[2], degs[3]));
    int nchunk = (maxdeg + 63) >> 6;

    float4 ad = *(const float4*)(adst + (size_t)node * 4);
    const float* asrc_g = asrc + (size_t)graph * NN * 4;
    const float* hg = hlin + ((size_t)graph * NN << 8);

    float4 acc = make_float4(0.f, 0.f, 0.f, 0.f);
    float4 ssum = make_float4(0.f, 0.f, 0.f, 0.f);
    for (int c = 0; c < nchunk; ++c) {
        int e0 = beg + (c << 6);
        int myedge = e0 + lane;
        float4 p = make_float4(0.f, 0.f, 0.f, 0.f);
        int src = 0;
        if (myedge < end) {
            src = csr[myedge];
            float4 a = *(const float4*)(asrc_g + (size_t)src * 4);
            p.x = __expf(leaky_(a.x + ad.x));
            p.y = __expf(leaky_(a.y + ad.y));
            p.z = __expf(leaky_(a.z + ad.z));
            p.w = __expf(leaky_(a.w + ad.w));
        }
        // butterfly sum of this chunk's weights
        float4 t = p;
#pragma unroll
        for (int off = 1; off < 64; off <<= 1) {
            t.x += __shfl_xor(t.x, off, 64);
            t.y += __shfl_xor(t.y, off, 64);
            t.z += __shfl_xor(t.z, off, 64);
            t.w += __shfl_xor(t.w, off, 64);
        }
        ssum.x += t.x; ssum.y += t.y; ssum.z += t.z; ssum.w += t.w;
        *(float4*)&pbuf[w][lane][0] = p;
        sbuf[w][lane] = src;
        __syncthreads();
        int cnt = end - e0;
        if (cnt > 64) cnt = 64;
        int cnt8 = (cnt + 7) & ~7;         // pad to x8: pbuf/sbuf zero-filled
        for (int e = 0; e < cnt8; e += 8) {
            float4 p0 = *(const float4*)&pbuf[w][e + 0][0];
            float4 p1 = *(const float4*)&pbuf[w][e + 1][0];
            float4 p2 = *(const float4*)&pbuf[w][e + 2][0];
            float4 p3 = *(const float4*)&pbuf[w][e + 3][0];
            float4 p4 = *(const float4*)&pbuf[w][e + 4][0];
            float4 p5 = *(const float4*)&pbuf[w][e + 5][0];
            float4 p6 = *(const float4*)&pbuf[w][e + 6][0];
            float4 p7 = *(const float4*)&pbuf[w][e + 7][0];
            int s0 = sbuf[w][e + 0], s1 = sbuf[w][e + 1];
            int s2 = sbuf[w][e + 2], s3 = sbuf[w][e + 3];
            int s4 = sbuf[w][e + 4], s5 = sbuf[w][e + 5];
            int s6 = sbuf[w][e + 6], s7 = sbuf[w][e + 7];
            int lo = lane << 2;
            float4 h0 = *(const float4*)(hg + (((size_t)s0) << 8) + lo);
            float4 h1 = *(const float4*)(hg + (((size_t)s1) << 8) + lo);
            float4 h2 = *(const float4*)(hg + (((size_t)s2) << 8) + lo);
            float4 h3 = *(const float4*)(hg + (((size_t)s3) << 8) + lo);
            float4 h4 = *(const float4*)(hg + (((size_t)s4) << 8) + lo);
            float4 h5 = *(const float4*)(hg + (((size_t)s5) << 8) + lo);
            float4 h6 = *(const float4*)(hg + (((size_t)s6) << 8) + lo);
            float4 h7 = *(const float4*)(hg + (((size_t)s7) << 8) + lo);
            acc.x = fmaf(p0.x, h0.x, acc.x); acc.y = fmaf(p0.y, h0.y, acc.y);
            acc.z = fmaf(p0.z, h0.z, acc.z); acc.w = fmaf(p0.w, h0.w, acc.w);
            acc.x = fmaf(p1.x, h1.x, acc.x); acc.y = fmaf(p1.y, h1.y, acc.y);
            acc.z = fmaf(p1.z, h1.z, acc.z); acc.w = fmaf(p1.w, h1.w, acc.w);
            acc.x = fmaf(p2.x, h2.x, acc.x); acc.y = fmaf(p2.y, h2.y, acc.y);
            acc.z = fmaf(p2.z, h2.z, acc.z); acc.w = fmaf(p2.w, h2.w, acc.w);
            acc.x = fmaf(p3.x, h3.x, acc.x); acc.y = fmaf(p3.y, h3.y, acc.y);
            acc.z = fmaf(p3.z, h3.z, acc.z); acc.w = fmaf(p3.w, h3.w, acc.w);
            acc.x = fmaf(p4.x, h4.x, acc.x); acc.y = fmaf(p4.y, h4.y, acc.y);
            acc.z = fmaf(p4.z, h4.z, acc.z); acc.w = fmaf(p4.w, h4.w, acc.w);
            acc.x = fmaf(p5.x, h5.x, acc.x); acc.y = fmaf(p5.y, h5.y, acc.y);
            acc.z = fmaf(p5.z, h5.z, acc.z); acc.w = fmaf(p5.w, h5.w, acc.w);
            acc.x = fmaf(p6.x, h6.x, acc.x); acc.y = fmaf(p6.y, h6.y, acc.y);
            acc.z = fmaf(p6.z, h6.z, acc.z); acc.w = fmaf(p6.w, h6.w, acc.w);
            acc.x = fmaf(p7.x, h7.x, acc.x); acc.y = fmaf(p7.y, h7.y, acc.y);
            acc.z = fmaf(p7.z, h7.z, acc.z); acc.w = fmaf(p7.w, h7.w, acc.w);
        }
        __syncthreads();
    }
    float o = 0.25f * (acc.x / ssum.x + acc.y / ssum.y + acc.z / ssum.z + acc.w / ssum.w)
            + bias[lane];
    if (do_relu) o = fmaxf(o, 0.f);
    out[((size_t)node << 6) + lane] = o;
}

// ---------------- GRU input-side GEMM (FROZEN) ----------------
template <int MODE>
__global__ __launch_bounds__(192, 4) void gru_gi(
    const float* __restrict__ in, const float* __restrict__ Wih,
    const float* __restrict__ bih, float* __restrict__ giseq) {
    const int ROWS = 10;  // 3200 blocks * 10 = 32000 (t,row) pairs
    int j = threadIdx.x;  // 0..191
    float wrow[64];
#pragma unroll
    for (int f4 = 0; f4 < 16; ++f4) {
        float4 w = *(const float4*)(Wih + (size_t)j * 64 + f4 * 4);
        wrow[4 * f4 + 0] = w.x; wrow[4 * f4 + 1] = w.y;
        wrow[4 * f4 + 2] = w.z; wrow[4 * f4 + 3] = w.w;
    }
    PIN64_(wrow)
    float bj = bih[j];
    int q0 = blockIdx.x * ROWS;
    int t = q0 / NROWS;            // constant per block (NROWS % ROWS == 0)
    int r0 = q0 - t * NROWS;
    for (int rr = 0; rr < ROWS; rr += 2) {
        const float *xa, *xb;
        if (MODE == 0) {
            int ra = r0 + rr, rb = ra + 1;
            int ba = ra / NN, na = ra - ba * NN;
            int bb2 = rb / NN, nb = rb - bb2 * NN;
            xa = in + (((size_t)(ba * TT + t) * NN + na) << 6);
            xb = in + (((size_t)(bb2 * TT + t) * NN + nb) << 6);
        } else {
            xa = in + ((size_t)(q0 + rr) << 6);
            xb = xa + 64;
        }
        float acca = bj, accb = bj;
#pragma unroll
        for (int f4 = 0; f4 < 16; ++f4) {
            float4 a4 = *(const float4*)(xa + f4 * 4);
            float4 b4 = *(const float4*)(xb + f4 * 4);
            acca = fmaf(a4.x, wrow[4 * f4 + 0], acca);
            acca = fmaf(a4.y, wrow[4 * f4 + 1], acca);
            acca = fmaf(a4.z, wrow[4 * f4 + 2], acca);
            acca = fmaf(a4.w, wrow[4 * f4 + 3], acca);
            accb = fmaf(b4.x, wrow[4 * f4 + 0], accb);
            accb = fmaf(b4.y, wrow[4 * f4 + 1], accb);
            accb = fmaf(b4.z, wrow[4 * f4 + 2], accb);
            accb = fmaf(b4.w, wrow[4 * f4 + 3], accb);
        }
        giseq[(size_t)(q0 + rr) * 192 + j] = acca;
        giseq[(size_t)(q0 + rr + 1) * 192 + j] = accb;
    }
}

// ---------------- GRU recurrence v2 (FROZEN) ----------------
template <int LAYER>
__global__ __launch_bounds__(128) void gru_rec(
    const float* __restrict__ giseq, const float* __restrict__ Whh,
    const float* __restrict__ bhh, float* __restrict__ outseq) {
    __shared__ float hs[8][64];       // 2 waves * 4 rows, wave-private regions
    int tid = threadIdx.x;
    int ch = tid & 63, w = tid >> 6;  // w in {0,1}
    float wr[64], wz[64], wn[64];
#pragma unroll
    for (int k4 = 0; k4 < 16; ++k4) {
        float4 a = *(const float4*)(Whh + (size_t)ch * 64 + k4 * 4);
        float4 b = *(const float4*)(Whh + (size_t)(64 + ch) * 64 + k4 * 4);
        float4 c = *(const float4*)(Whh + (size_t)(128 + ch) * 64 + k4 * 4);
        wr[4*k4+0] = a.x; wr[4*k4+1] = a.y; wr[4*k4+2] = a.z; wr[4*k4+3] = a.w;
        wz[4*k4+0] = b.x; wz[4*k4+1] = b.y; wz[4*k4+2] = b.z; wz[4*k4+3] = b.w;
        wn[4*k4+0] = c.x; wn[4*k4+1] = c.y; wn[4*k4+2] = c.z; wn[4*k4+3] = c.w;
    }
    float br = bhh[ch], bz = bhh[64 + ch], bn = bhh[128 + ch];
    int row0 = blockIdx.x * 8 + w * 4;
    float hprev[4];
#pragma unroll
    for (int r = 0; r < 4; ++r) { hs[w * 4 + r][ch] = 0.f; hprev[r] = 0.f; }

    for (int t = 0; t < TT; ++t) {
#pragma unroll
        for (int r = 0; r < 4; ++r) {
            int row = row0 + r;
            const float* gp = giseq + ((size_t)(t * NROWS + row)) * 192;
            float gir = gp[ch], giz = gp[64 + ch], gin = gp[128 + ch];
            float ar = br, az = bz, an = bn;
#pragma unroll
            for (int k4 = 0; k4 < 16; ++k4) {
                float4 h4 = *(const float4*)&hs[w * 4 + r][k4 * 4];  // broadcast
                ar = fmaf(h4.x, wr[4*k4+0], ar); ar = fmaf(h4.y, wr[4*k4+1], ar);
                ar = fmaf(h4.z, wr[4*k4+2], ar); ar = fmaf(h4.w, wr[4*k4+3], ar);
                az = fmaf(h4.x, wz[4*k4+0], az); az = fmaf(h4.y, wz[4*k4+1], az);
                az = fmaf(h4.z, wz[4*k4+2], az); az = fmaf(h4.w, wz[4*k4+3], az);
                an = fmaf(h4.x, wn[4*k4+0], an); an = fmaf(h4.y, wn[4*k4+1], an);
                an = fmaf(h4.z, wn[4*k4+2], an); an = fmaf(h4.w, wn[4*k4+3], an);
            }
            float rg = sigmoidf_(gir + ar);
            float zg = sigmoidf_(giz + az);
            float ng = tanhf_(gin + rg * an);
            float hnew = (1.f - zg) * ng + zg * hprev[r];
            hprev[r] = hnew;
            hs[w * 4 + r][ch] = hnew;   // same-wave LDS dep, compiler orders via lgkmcnt
            if (LAYER == 0)
                outseq[(((size_t)(t * NROWS + row)) << 6) + ch] = hnew;
        }
    }
    if (LAYER == 1) {
#pragma unroll
        for (int r = 0; r < 4; ++r)
            outseq[(((size_t)(row0 + r)) << 6) + ch] = hprev[r];
    }
}

// ---------------- final MLP ----------------
__global__ __launch_bounds__(64) void mlp_head(
    const float* __restrict__ hT, const float* __restrict__ pW1,
    const float* __restrict__ pb1, const float* __restrict__ pW2,
    const float* __restrict__ pb2, float* __restrict__ out) {
    int r = blockIdx.x, lane = threadIdx.x;
    __shared__ float hrow[64];
    __shared__ float mid[64];
    hrow[lane] = hT[((size_t)r << 6) + lane];
    __syncthreads();
    float acc = pb1[lane];
#pragma unroll
    for (int k = 0; k < 64; ++k) acc = fmaf(hrow[k], pW1[k * 64 + lane], acc);
    mid[lane] = fmaxf(acc, 0.f);
    __syncthreads();
    if (lane < 10) {
        float o = pb2[lane];
#pragma unroll
        for (int k = 0; k < 64; ++k) o = fmaf(mid[k], pW2[k * 10 + lane], o);
        out[(size_t)r * 10 + lane] = o;
    }
}

// ---------------- launch ----------------
extern "C" void kernel_launch(void* const* d_in, const int* in_sizes, int n_in,
                              void* d_out, int out_size, void* d_ws, size_t ws_size,
                              hipStream_t stream) {
    (void)in_sizes; (void)n_in; (void)out_size; (void)ws_size;
    const float* x    = (const float*)d_in[0];
    const int*   ei   = (const int*)d_in[1];
    const float* W1   = (const float*)d_in[3];
    const float* as1  = (const float*)d_in[4];
    const float* ad1  = (const float*)d_in[5];
    const float* b1   = (const float*)d_in[6];
    const float* W2   = (const float*)d_in[7];
    const float* as2  = (const float*)d_in[8];
    const float* ad2  = (const float*)d_in[9];
    const float* b2   = (const float*)d_in[10];
    const float* Wih0 = (const float*)d_in[13];
    const float* Whh0 = (const float*)d_in[14];
    const float* bih0 = (const float*)d_in[15];
    const float* bhh0 = (const float*)d_in[16];
    const float* Wih1 = (const float*)d_in[17];
    const float* Whh1 = (const float*)d_in[18];
    const float* bih1 = (const float*)d_in[19];
    const float* bhh1 = (const float*)d_in[20];
    const float* pW1  = (const float*)d_in[21];
    const float* pb1  = (const float*)d_in[22];
    const float* pW2  = (const float*)d_in[23];
    const float* pb2  = (const float*)d_in[24];
    float* out = (float*)d_out;

    // workspace layout (bytes); overlays noted
    char* ws = (char*)d_ws;
    float* hlin  = (float*)(ws + 0);           // 32,768,000  (overlay: giseq 24.58MB)
    float* giseq = hlin;
    float* asrc  = (float*)(ws + 32768000);    // 512,000     (overlay: hT 1MB spans asrc+adst)
    float* hT    = asrc;
    float* adst  = (float*)(ws + 33280000);    // 512,000
    float* gat1  = (float*)(ws + 33792000);    // 8,192,000   (overlay: h1seq)
    float* h1seq = gat1;
    float* gat2  = (float*)(ws + 41984000);    // 8,192,000
    int* counts  = (int*)(ws + 50176000);      // 128,000
    int* cursor  = (int*)(ws + 50304000);      // 128,000
    int* offs    = (int*)(ws + 50432000);      // 128,004 (padded to 128,256)
    int* csr     = (int*)(ws + 50560256);      // 2,176,000  -> total 52.7MB

    hipMemsetAsync(counts, 0, 2 * GN * sizeof(int), stream);  // counts + cursor (adjacent)

    dim3 egrid((E2 + 255) / 256, GG);
    count_edges<<<egrid, 256, 0, stream>>>(ei, counts);
    scan_offsets_pg<<<GG, 256, 0, stream>>>(counts, offs);
    scatter_edges<<<egrid, 256, 0, stream>>>(ei, offs, cursor, csr);

    gat_linear<0><<<GG * 100, 256, 0, stream>>>(x, W1, as1, ad1, hlin, asrc, adst);
    gat_edge<<<GN / 4, 256, 0, stream>>>(hlin, asrc, adst, offs, csr, b1, gat1, 1);
    gat_linear<1><<<GG * 100, 256, 0, stream>>>(gat1, W2, as2, ad2, hlin, asrc, adst);
    gat_edge<<<GN / 4, 256, 0, stream>>>(hlin, asrc, adst, offs, csr, b2, gat2, 0);

    gru_gi<0><<<3200, 192, 0, stream>>>(gat2, Wih0, bih0, giseq);
    gru_rec<0><<<500, 128, 0, stream>>>(giseq, Whh0, bhh0, h1seq);
    gru_gi<1><<<3200, 192, 0, stream>>>(h1seq, Wih1, bih1, giseq);
    gru_rec<1><<<500, 128, 0, stream>>>(giseq, Whh1, bhh1, hT);

    mlp_head<<<NROWS, 64, 0, stream>>>(hT, pW1, pb1, pW2, pb2, out);
}